// Round 15
// baseline (31.809 us; speedup 1.0000x reference)
//
#include <hip/hip_runtime.h>
#include <math.h>

#define CI 64
#define CO 128
#define CX 69
#define LPIX 1024   // 32*32

typedef __attribute__((ext_vector_type(8))) short bf16x8;
typedef __attribute__((ext_vector_type(4))) float f32x4;

__device__ __forceinline__ unsigned short f2bf(float f) {
  unsigned u = __float_as_uint(f);
  unsigned r = (u + 0x7fffu + ((u >> 16) & 1u)) >> 16;
  return (unsigned short)r;
}

// ---------------------------------------------------------------------------
// convFused: conv3x3 (zero-pad) via bf16 MFMA 16x16x32 + fused epilogue.
// SELF-CONTAINED (prepW absorbed): each wave converts its own 16-co weight
// slice f32->bf16 in-register. 4 sequential 36-float scopes (9 dwordx4 +
// 4x9 transpose + v_cvt_pk_bf16_f32, numerics validated r11) with
// sched_barrier(0) pinning -> peak VGPR ~118 under the (512,4) cap of 128.
// B staged FIRST so its registers are dead before the weight scopes.
// grid 512 = 16 b x 16 row-pairs x 2 co-halves; 512 thr = 8 waves.
// Everything else identical to r12 (session-best structure).
// ---------------------------------------------------------------------------
__launch_bounds__(512, 4)
__global__ void convFused(const float* __restrict__ xg,
                          const float* __restrict__ cwg,
                          const float* __restrict__ cbg,
                          const float* __restrict__ w2g,
                          const float* __restrict__ skg,
                          float* __restrict__ qp,
                          float* __restrict__ outg) {
  __shared__ char arena[18432];       // ldsB (18432 B) -> lds_c (16384 B)
  __shared__ float lds_sx[5 * 144];   // shape rows, edge-clamped
  __shared__ float qred[8][64];

  unsigned short* ldsB = (unsigned short*)arena;
  float* lds_c = (float*)arena;

  const int tid = threadIdx.x;
  const int blk = blockIdx.x;
  const int coh = blk & 1;
  const int rp  = (blk >> 1) & 15;
  const int b   = blk >> 5;
  const int r0  = rp * 2;

  const int w    = tid >> 6;
  const int lane = tid & 63;
  const int rsel = w >> 2;          // MFMA-phase: wave's row within pair
  const int ct   = w & 3;           // MFMA-phase: co-16-tile within half
  const int n16  = lane & 15;
  const int kq   = lane >> 4;

  const float* xb = xg + (size_t)b * CX * LPIX;
  const float* xs = xb + CI * LPIX;

  // ---- stage B FIRST (frees its registers before the weight scopes):
  // x rows r0-1..r0+2, col slot s holds global col s-1, bf16, ci-group
  // XOR-swizzled by (slot&7). Zero rows/cols OOB. 4 dwordx4/thread.
  {
    const int row  = tid >> 7;         // 0..3
    const int cip  = (tid >> 2) & 31;  // ci pair
    const int colq = tid & 3;          // 8-col group
    const int ci   = cip * 2;
    const int c0   = colq * 8;
    const int grow = r0 - 1 + row;
    f32x4 u0a = {}, u0b = {}, u1a = {}, u1b = {};
    if ((unsigned)grow < 32u) {
      const float* p0 = xb + ci * LPIX + grow * 32 + c0;
      u0a = *(const f32x4*)p0;          u0b = *(const f32x4*)(p0 + 4);
      u1a = *(const f32x4*)(p0 + LPIX); u1b = *(const f32x4*)(p0 + LPIX + 4);
    }
    #pragma unroll
    for (int cc = 0; cc < 8; ++cc) {
      float f0 = (cc < 4) ? u0a[cc] : u0b[cc - 4];
      float f1 = (cc < 4) ? u1a[cc] : u1b[cc - 4];
      unsigned v = (unsigned)f2bf(f0) | ((unsigned)f2bf(f1) << 16);
      const int slot  = c0 + cc + 1;   // 1..32
      const int gslot = ((ci >> 3) << 3) ^ ((slot & 7) << 3);
      ((unsigned*)ldsB)[(((row * 36 + slot) << 6) + gslot + (ci & 7)) >> 1] = v;
    }
    // zero pad slots 0,33,34,35 (4 rows x 32 ci-pairs each = 512 u32)
    {
      const int prw = tid >> 7;
      const int s4  = (tid >> 5) & 3;
      const int sl  = (s4 == 0) ? 0 : (32 + s4);
      const int ci2 = (tid & 31) * 2;
      const int gsl = ((ci2 >> 3) << 3) ^ ((sl & 7) << 3);
      ((unsigned*)ldsB)[(((prw * 36 + sl) << 6) + gsl + (ci2 & 7)) >> 1] = 0;
    }
  }

  // ---- stage shape rows (edge clamp) for the epilogue
  for (int idx = tid; idx < 5 * 144; idx += 512) {
    int c = idx / 144, rem = idx - c * 144;
    int s = rem / 36, j = rem - s * 36;
    int hh = r0 - 1 + s; hh = hh < 0 ? 0 : (hh > 31 ? 31 : hh);
    int col = j - 1;     col = col < 0 ? 0 : (col > 31 ? 31 : col);
    lds_sx[idx] = xs[c * LPIX + hh * 32 + col];
  }

  // ---- A fragments: in-register transpose+cvt of this wave's 16-co weights.
  // cwg[co][ci][tap]: lane's elems ci = ch*32 + kq*8 + e are the contiguous
  // float run at (co*576 + (ch*32+kq*8)*9), processed 4 ci-rows at a time.
  // aw[ch][tap].v elem e == bf16(W[co][ch*32+kq*8+e][tap])  (r9+-validated
  // fragment; cvt_pk numerics validated r11).
  union AU { unsigned u[4]; bf16x8 v; };
  AU aw[2][9];
  {
    const float* wbase = cwg + (size_t)(coh * 64 + ct * 16 + n16) * 576;
    #pragma unroll
    for (int ch = 0; ch < 2; ++ch) {
      #pragma unroll
      for (int s = 0; s < 2; ++s) {
        f32x4 buf[9];   // [ci_local 0..3][tap 0..8] contiguous 36 floats
        const float* p = wbase + (ch * 32 + kq * 8 + s * 4) * 9;
        #pragma unroll
        for (int i = 0; i < 9; ++i) buf[i] = *(const f32x4*)(p + i * 4);
        #pragma unroll
        for (int tap = 0; tap < 9; ++tap) {
          #pragma unroll
          for (int pp = 0; pp < 2; ++pp) {
            const int e0 = (2 * pp) * 9 + tap;
            const int e1 = (2 * pp + 1) * 9 + tap;
            float lo = buf[e0 >> 2][e0 & 3];
            float hi = buf[e1 >> 2][e1 & 3];
            asm("v_cvt_pk_bf16_f32 %0, %1, %2"
                : "=v"(aw[ch][tap].u[s * 2 + pp]) : "v"(lo), "v"(hi));
          }
        }
        __builtin_amdgcn_sched_barrier(0);  // pin scope order: one buf live
      }
    }
  }
  __syncthreads();

  // ---- barrier-free tap loop: per tap 4 ds_read_b128 + 4 MFMA (A in regs)
  f32x4 acc[2] = {};
  #pragma unroll
  for (int tap = 0; tap < 9; ++tap) {
    const int dr = tap / 3, dc = tap % 3;
    const int rowst = rsel + dr;                 // staged row 0..3
    #pragma unroll
    for (int ch = 0; ch < 2; ++ch) {             // ci halves
      const int g = (ch << 2) + kq;              // ci group 0..7
      #pragma unroll
      for (int pt = 0; pt < 2; ++pt) {
        const int slot = pt * 16 + n16 + dc;     // 0..33
        const int gs = (g ^ (slot & 7)) << 3;
        bf16x8 bfr = *(const bf16x8*)(ldsB + ((rowst * 36 + slot) << 6) + gs);
        acc[pt] = __builtin_amdgcn_mfma_f32_16x16x32_bf16(aw[ch][tap].v, bfr,
                                                          acc[pt], 0, 0, 0);
      }
    }
  }
  __syncthreads();   // all waves done reading ldsB before lds_c overwrites it

  // ---- transpose acc through LDS: [px 0..63][co_l 0..63], XOR-swizzled f32x4
  // C layout (validated r5-r14): col(px in tile)=n16, row(co in tile)=kq*4+reg
  #pragma unroll
  for (int pt = 0; pt < 2; ++pt) {
    const int pxl = rsel * 32 + pt * 16 + n16;
    const int cog = ct * 4 + kq;                 // co_l/4 group: 0..15
    const int sg  = cog ^ (pxl & 7);
    *(f32x4*)&lds_c[pxl * 64 + sg * 4] = acc[pt];
  }
  __syncthreads();

  // ---- epilogue: wave wS -> co chunk [wS*8, wS*8+8) of this half; lane = px
  const int wS   = __builtin_amdgcn_readfirstlane(w);
  const int co0g = coh * 64 + wS * 8;
  const int pxl  = lane;

  float cvals[8];
  #pragma unroll
  for (int g = 0; g < 2; ++g) {
    const int cog = wS * 2 + g;
    const int sg  = cog ^ (pxl & 7);
    *(f32x4*)&cvals[g * 4] = *(const f32x4*)&lds_c[pxl * 64 + sg * 4];
  }

  // shape windows into registers (center-relative for channels 0,1)
  const int xbase = (pxl >> 5) * 36 + (pxl & 31);
  float swv[45];
  {
    const float c0 = lds_sx[0 * 144 + 37 + xbase];
    const float c1 = lds_sx[1 * 144 + 37 + xbase];
    #pragma unroll
    for (int c = 0; c < 5; ++c) {
      float ctr = (c == 0) ? c0 : ((c == 1) ? c1 : 0.f);
      #pragma unroll
      for (int s = 0; s < 3; ++s)
        #pragma unroll
        for (int dc = 0; dc < 3; ++dc)
          swv[c * 9 + s * 3 + dc] = lds_sx[c * 144 + s * 36 + dc + xbase] - ctr;
    }
  }

  // sd: per co a CONTIGUOUS wave-uniform 45-float run (merged s_loads)
  // + pure VALU (r12-validated: fixes the scalar-K$ thrash).
  float sd[8];
  #pragma unroll
  for (int k = 0; k < 8; ++k) {
    const float* kp = skg + (size_t)(co0g + k) * 45;   // wave-uniform
    float s = 0.f;
    #pragma unroll
    for (int j = 0; j < 45; ++j)
      s += fabsf(swv[j] - kp[j]);
    sd[k] = s;
  }

  // bias + saf = relu(conv/(sd+1)) + store + q partial
  float qpv = 0.f;
  float* ob = outg + ((size_t)b * 133 + co0g) * LPIX + (r0 + (pxl >> 5)) * 32 + (pxl & 31);
  #pragma unroll
  for (int k = 0; k < 8; ++k) {
    float v = (cvals[k] + cbg[co0g + k]) * __builtin_amdgcn_rcpf(sd[k] + 1.0f);
    v = v > 0.f ? v : 0.f;
    ob[(size_t)k * LPIX] = v;
    qpv = fmaf(v, w2g[co0g + k], qpv);
  }

  // in-block q reduction over the 8 waves (this half's 64 co)
  qred[w][lane] = qpv;
  __syncthreads();
  if (tid < 64) {
    float q = 0.f;
    #pragma unroll
    for (int w8 = 0; w8 < 8; ++w8) q += qred[w8][tid];
    qp[coh * 16384 + b * LPIX + r0 * 32 + tid] = q;
  }
}

// ---------------------------------------------------------------------------
// statsB (r12-validated): combine q halves, 3x3 zero-padded softmax +
// weighted window stats.
// ---------------------------------------------------------------------------
__launch_bounds__(64)
__global__ void statsB(const float* __restrict__ xg,
                       const float* __restrict__ qp,
                       const float* __restrict__ b2g,
                       float* __restrict__ outg) {
  const int gid = blockIdx.x * 64 + threadIdx.x;  // 0..16383
  const int b = gid >> 10;
  const int h = (gid >> 5) & 31;
  const int w = gid & 31;

  const float b2 = b2g[0];
  const float* q0 = qp + (size_t)b * LPIX;
  float qv[9];
  float m = -1e30f;
  #pragma unroll
  for (int t = 0; t < 9; ++t) {
    int hh = h + t / 3 - 1, wc = w + t % 3 - 1;
    float v = 0.f;  // zero padding participates in softmax
    if ((unsigned)hh < 32u && (unsigned)wc < 32u) {
      int off = hh * 32 + wc;
      v = (q0[off] + q0[16384 + off] + b2) * 0.08838834764831845f;  // 1/sqrt(128)
    }
    qv[t] = v;
    m = fmaxf(m, v);
  }
  float ssum = 0.f;
  #pragma unroll
  for (int t = 0; t < 9; ++t) { qv[t] = expf(qv[t] - m); ssum += qv[t]; }
  const float inv = 1.f / ssum;

  const float* xs = xg + ((size_t)b * CX + CI) * LPIX;
  float um0[9], um1[9];
  float m0 = 0.f, m1 = 0.f, v1a = 0.f, v1b = 0.f, c1 = 0.f;
  #pragma unroll
  for (int t = 0; t < 9; ++t) {
    int hh = h + t / 3 - 1; hh = hh < 0 ? 0 : (hh > 31 ? 31 : hh);  // edge pad
    int wc = w + t % 3 - 1; wc = wc < 0 ? 0 : (wc > 31 ? 31 : wc);
    int off = hh * 32 + wc;
    float quv = qv[t] * inv;
    qv[t] = quv;
    float a0 = xs[off];
    float a1 = xs[LPIX + off];
    float b0 = xs[2 * LPIX + off];
    float b1 = xs[3 * LPIX + off];
    float cc = xs[4 * LPIX + off];
    um0[t] = a0; um1[t] = a1;
    m0 = fmaf(a0, quv, m0);
    m1 = fmaf(a1, quv, m1);
    v1a = fmaf(b0, quv, v1a);
    v1b = fmaf(b1, quv, v1b);
    c1 = fmaf(cc, quv, c1);
  }
  float var0 = v1a, var1 = v1b, cov = c1;
  #pragma unroll
  for (int t = 0; t < 9; ++t) {
    float d0 = um0[t] - m0, d1 = um1[t] - m1;
    var0 = fmaf(d0 * d0, qv[t], var0);
    var1 = fmaf(d1 * d1, qv[t], var1);
    cov  = fmaf(d0 * d1, qv[t], cov);
  }
  float* ob = outg + ((size_t)b * 133 + 128) * LPIX + h * 32 + w;
  ob[0 * LPIX] = m0;
  ob[1 * LPIX] = m1;
  ob[2 * LPIX] = var0;
  ob[3 * LPIX] = var1;
  ob[4 * LPIX] = cov;
}

extern "C" void kernel_launch(void* const* d_in, const int* in_sizes, int n_in,
                              void* d_out, int out_size, void* d_ws, size_t ws_size,
                              hipStream_t stream) {
  const float* x  = (const float*)d_in[0];
  const float* cw = (const float*)d_in[1];
  const float* cb = (const float*)d_in[2];
  const float* w2 = (const float*)d_in[3];
  const float* b2 = (const float*)d_in[4];
  const float* sk = (const float*)d_in[5];
  float* out = (float*)d_out;

  float* qp = (float*)d_ws;   // f32[2*16*1024] = 128 KB

  convFused<<<dim3(512), dim3(512), 0, stream>>>(x, cw, cb, w2, sk, qp, out);
  statsB<<<dim3(256), dim3(64), 0, stream>>>(x, qp, b2, out);
}

// Round 16
// 29.623 us; speedup vs baseline: 1.0738x; 1.0738x over previous
//
#include <hip/hip_runtime.h>
#include <math.h>

#define CI 64
#define CO 128
#define CX 69
#define LPIX 1024   // 32*32

typedef __attribute__((ext_vector_type(8))) short bf16x8;
typedef __attribute__((ext_vector_type(4))) float f32x4;

// ws byte offsets
#define WMF_OFF  0                        // u16[128][9][64] = 147456 B
#define QP_OFF   147456                   // f32[2*16*1024]  = 131072 B

__device__ __forceinline__ unsigned short f2bf(float f) {
  unsigned u = __float_as_uint(f);
  unsigned r = (u + 0x7fffu + ((u >> 16) & 1u)) >> 16;
  return (unsigned short)r;
}

// ---------------------------------------------------------------------------
// prepW: weights -> wmf[co][tap][ci] bf16 (a lane's 9-tap A-fragment set is
// one base pointer + tap*128B/ch*64B immediate offsets; layout validated r9+).
// ---------------------------------------------------------------------------
__launch_bounds__(256)
__global__ void prepW(const float* __restrict__ cwg,
                      unsigned short* __restrict__ wmf) {
  int i = blockIdx.x * 256 + threadIdx.x;
  if (i < 128 * 9 * 64) {
    int co = i / 576, rem = i - co * 576;
    int tap = rem >> 6, ci = rem & 63;
    wmf[i] = f2bf(cwg[co * 576 + ci * 9 + tap]);
  }
}

// ---------------------------------------------------------------------------
// convFused (r12, session best): conv3x3 (zero-pad) via bf16 MFMA 16x16x32 +
// fused epilogue (bias, L1 shape-distance, saf, q partial).
// grid 512 = 16 b x 16 row-pairs x 2 co-halves; 512 thr = 8 waves.
// Wave = (row within pair, co-16-tile): A (9 taps x 2 ci-halves) pre-loaded
// into 18 b128 registers; zero in-loop barriers. B staged in LDS
// (r7-validated swizzled image) via 4 dwordx4 loads/thread.
// Epilogue: acc transposed through LDS (aliases dead ldsB), wave = 8-co
// chunk, lane = pixel; sd reads skg[co][0..45] contiguously (r12-validated:
// wave-uniform merged s_loads, no scalar-K$ thrash).
// ---------------------------------------------------------------------------
__launch_bounds__(512, 4)
__global__ void convFused(const float* __restrict__ xg,
                          const unsigned short* __restrict__ wmfg,
                          const float* __restrict__ cbg,
                          const float* __restrict__ w2g,
                          const float* __restrict__ skg,
                          float* __restrict__ qp,
                          float* __restrict__ outg) {
  __shared__ char arena[18432];       // ldsB (18432 B) -> lds_c (16384 B)
  __shared__ float lds_sx[5 * 144];   // shape rows, edge-clamped
  __shared__ float qred[8][64];

  unsigned short* ldsB = (unsigned short*)arena;
  float* lds_c = (float*)arena;

  const int tid = threadIdx.x;
  const int blk = blockIdx.x;
  const int coh = blk & 1;
  const int rp  = (blk >> 1) & 15;
  const int b   = blk >> 5;
  const int r0  = rp * 2;

  const int w    = tid >> 6;
  const int lane = tid & 63;
  const int rsel = w >> 2;          // MFMA-phase: wave's row within pair
  const int ct   = w & 3;           // MFMA-phase: co-16-tile within half
  const int n16  = lane & 15;
  const int kq   = lane >> 4;

  const float* xb = xg + (size_t)b * CX * LPIX;
  const float* xs = xb + CI * LPIX;

  // ---- A fragments into registers: 9 taps x 2 ci-halves, one b128 each.
  bf16x8 areg[2][9];
  {
    const unsigned short* abase =
        wmfg + (size_t)(coh * 64 + ct * 16 + n16) * 576 + kq * 8;
    #pragma unroll
    for (int ch = 0; ch < 2; ++ch)
      #pragma unroll
      for (int tap = 0; tap < 9; ++tap)
        areg[ch][tap] = *(const bf16x8*)(abase + tap * 64 + ch * 32);
  }

  // ---- stage B: x rows r0-1..r0+2, col slot s holds global col s-1, bf16,
  // ci-group XOR-swizzled by (slot&7). Zero rows/cols OOB. 4 dwordx4/thread.
  {
    const int row  = tid >> 7;         // 0..3
    const int cip  = (tid >> 2) & 31;  // ci pair
    const int colq = tid & 3;          // 8-col group
    const int ci   = cip * 2;
    const int c0   = colq * 8;
    const int grow = r0 - 1 + row;
    f32x4 u0a = {}, u0b = {}, u1a = {}, u1b = {};
    if ((unsigned)grow < 32u) {
      const float* p0 = xb + ci * LPIX + grow * 32 + c0;
      u0a = *(const f32x4*)p0;          u0b = *(const f32x4*)(p0 + 4);
      u1a = *(const f32x4*)(p0 + LPIX); u1b = *(const f32x4*)(p0 + LPIX + 4);
    }
    #pragma unroll
    for (int cc = 0; cc < 8; ++cc) {
      float f0 = (cc < 4) ? u0a[cc] : u0b[cc - 4];
      float f1 = (cc < 4) ? u1a[cc] : u1b[cc - 4];
      unsigned v = (unsigned)f2bf(f0) | ((unsigned)f2bf(f1) << 16);
      const int slot  = c0 + cc + 1;   // 1..32
      const int gslot = ((ci >> 3) << 3) ^ ((slot & 7) << 3);
      ((unsigned*)ldsB)[(((row * 36 + slot) << 6) + gslot + (ci & 7)) >> 1] = v;
    }
    // zero pad slots 0,33,34,35 (4 rows x 32 ci-pairs each = 512 u32)
    {
      const int prw = tid >> 7;
      const int s4  = (tid >> 5) & 3;
      const int sl  = (s4 == 0) ? 0 : (32 + s4);
      const int ci2 = (tid & 31) * 2;
      const int gsl = ((ci2 >> 3) << 3) ^ ((sl & 7) << 3);
      ((unsigned*)ldsB)[(((prw * 36 + sl) << 6) + gsl + (ci2 & 7)) >> 1] = 0;
    }
  }

  // ---- stage shape rows (edge clamp) for the epilogue
  for (int idx = tid; idx < 5 * 144; idx += 512) {
    int c = idx / 144, rem = idx - c * 144;
    int s = rem / 36, j = rem - s * 36;
    int hh = r0 - 1 + s; hh = hh < 0 ? 0 : (hh > 31 ? 31 : hh);
    int col = j - 1;     col = col < 0 ? 0 : (col > 31 ? 31 : col);
    lds_sx[idx] = xs[c * LPIX + hh * 32 + col];
  }
  __syncthreads();

  // ---- barrier-free tap loop: per tap 4 ds_read_b128 + 4 MFMA (A in regs)
  f32x4 acc[2] = {};
  #pragma unroll
  for (int tap = 0; tap < 9; ++tap) {
    const int dr = tap / 3, dc = tap % 3;
    const int rowst = rsel + dr;                 // staged row 0..3
    #pragma unroll
    for (int ch = 0; ch < 2; ++ch) {             // ci halves
      const int g = (ch << 2) + kq;              // ci group 0..7
      #pragma unroll
      for (int pt = 0; pt < 2; ++pt) {
        const int slot = pt * 16 + n16 + dc;     // 0..33
        const int gs = (g ^ (slot & 7)) << 3;
        bf16x8 bfr = *(const bf16x8*)(ldsB + ((rowst * 36 + slot) << 6) + gs);
        acc[pt] = __builtin_amdgcn_mfma_f32_16x16x32_bf16(areg[ch][tap], bfr,
                                                          acc[pt], 0, 0, 0);
      }
    }
  }
  __syncthreads();   // all waves done reading ldsB before lds_c overwrites it

  // ---- transpose acc through LDS: [px 0..63][co_l 0..63], XOR-swizzled f32x4
  // C layout (validated r5-r14): col(px in tile)=n16, row(co in tile)=kq*4+reg
  #pragma unroll
  for (int pt = 0; pt < 2; ++pt) {
    const int pxl = rsel * 32 + pt * 16 + n16;
    const int cog = ct * 4 + kq;                 // co_l/4 group: 0..15
    const int sg  = cog ^ (pxl & 7);
    *(f32x4*)&lds_c[pxl * 64 + sg * 4] = acc[pt];
  }
  __syncthreads();

  // ---- epilogue: wave wS -> co chunk [wS*8, wS*8+8) of this half; lane = px
  const int wS   = __builtin_amdgcn_readfirstlane(w);
  const int co0g = coh * 64 + wS * 8;
  const int pxl  = lane;

  float cvals[8];
  #pragma unroll
  for (int g = 0; g < 2; ++g) {
    const int cog = wS * 2 + g;
    const int sg  = cog ^ (pxl & 7);
    *(f32x4*)&cvals[g * 4] = *(const f32x4*)&lds_c[pxl * 64 + sg * 4];
  }

  // shape windows into registers (center-relative for channels 0,1)
  const int xbase = (pxl >> 5) * 36 + (pxl & 31);
  float swv[45];
  {
    const float c0 = lds_sx[0 * 144 + 37 + xbase];
    const float c1 = lds_sx[1 * 144 + 37 + xbase];
    #pragma unroll
    for (int c = 0; c < 5; ++c) {
      float ctr = (c == 0) ? c0 : ((c == 1) ? c1 : 0.f);
      #pragma unroll
      for (int s = 0; s < 3; ++s)
        #pragma unroll
        for (int dc = 0; dc < 3; ++dc)
          swv[c * 9 + s * 3 + dc] = lds_sx[c * 144 + s * 36 + dc + xbase] - ctr;
    }
  }

  // sd: per co a CONTIGUOUS wave-uniform 45-float run (merged s_loads)
  // + pure VALU (r12-validated: fixes the scalar-K$ thrash).
  float sd[8];
  #pragma unroll
  for (int k = 0; k < 8; ++k) {
    const float* kp = skg + (size_t)(co0g + k) * 45;   // wave-uniform
    float s = 0.f;
    #pragma unroll
    for (int j = 0; j < 45; ++j)
      s += fabsf(swv[j] - kp[j]);
    sd[k] = s;
  }

  // bias + saf = relu(conv/(sd+1)) + store + q partial
  float qpv = 0.f;
  float* ob = outg + ((size_t)b * 133 + co0g) * LPIX + (r0 + (pxl >> 5)) * 32 + (pxl & 31);
  #pragma unroll
  for (int k = 0; k < 8; ++k) {
    float v = (cvals[k] + cbg[co0g + k]) * __builtin_amdgcn_rcpf(sd[k] + 1.0f);
    v = v > 0.f ? v : 0.f;
    ob[(size_t)k * LPIX] = v;
    qpv = fmaf(v, w2g[co0g + k], qpv);
  }

  // in-block q reduction over the 8 waves (this half's 64 co)
  qred[w][lane] = qpv;
  __syncthreads();
  if (tid < 64) {
    float q = 0.f;
    #pragma unroll
    for (int w8 = 0; w8 < 8; ++w8) q += qred[w8][tid];
    qp[coh * 16384 + b * LPIX + r0 * 32 + tid] = q;
  }
}

// ---------------------------------------------------------------------------
// statsB (r12-validated): combine q halves, 3x3 zero-padded softmax +
// weighted window stats.
// ---------------------------------------------------------------------------
__launch_bounds__(64)
__global__ void statsB(const float* __restrict__ xg,
                       const float* __restrict__ qp,
                       const float* __restrict__ b2g,
                       float* __restrict__ outg) {
  const int gid = blockIdx.x * 64 + threadIdx.x;  // 0..16383
  const int b = gid >> 10;
  const int h = (gid >> 5) & 31;
  const int w = gid & 31;

  const float b2 = b2g[0];
  const float* q0 = qp + (size_t)b * LPIX;
  float qv[9];
  float m = -1e30f;
  #pragma unroll
  for (int t = 0; t < 9; ++t) {
    int hh = h + t / 3 - 1, wc = w + t % 3 - 1;
    float v = 0.f;  // zero padding participates in softmax
    if ((unsigned)hh < 32u && (unsigned)wc < 32u) {
      int off = hh * 32 + wc;
      v = (q0[off] + q0[16384 + off] + b2) * 0.08838834764831845f;  // 1/sqrt(128)
    }
    qv[t] = v;
    m = fmaxf(m, v);
  }
  float ssum = 0.f;
  #pragma unroll
  for (int t = 0; t < 9; ++t) { qv[t] = expf(qv[t] - m); ssum += qv[t]; }
  const float inv = 1.f / ssum;

  const float* xs = xg + ((size_t)b * CX + CI) * LPIX;
  float um0[9], um1[9];
  float m0 = 0.f, m1 = 0.f, v1a = 0.f, v1b = 0.f, c1 = 0.f;
  #pragma unroll
  for (int t = 0; t < 9; ++t) {
    int hh = h + t / 3 - 1; hh = hh < 0 ? 0 : (hh > 31 ? 31 : hh);  // edge pad
    int wc = w + t % 3 - 1; wc = wc < 0 ? 0 : (wc > 31 ? 31 : wc);
    int off = hh * 32 + wc;
    float quv = qv[t] * inv;
    qv[t] = quv;
    float a0 = xs[off];
    float a1 = xs[LPIX + off];
    float b0 = xs[2 * LPIX + off];
    float b1 = xs[3 * LPIX + off];
    float cc = xs[4 * LPIX + off];
    um0[t] = a0; um1[t] = a1;
    m0 = fmaf(a0, quv, m0);
    m1 = fmaf(a1, quv, m1);
    v1a = fmaf(b0, quv, v1a);
    v1b = fmaf(b1, quv, v1b);
    c1 = fmaf(cc, quv, c1);
  }
  float var0 = v1a, var1 = v1b, cov = c1;
  #pragma unroll
  for (int t = 0; t < 9; ++t) {
    float d0 = um0[t] - m0, d1 = um1[t] - m1;
    var0 = fmaf(d0 * d0, qv[t], var0);
    var1 = fmaf(d1 * d1, qv[t], var1);
    cov  = fmaf(d0 * d1, qv[t], cov);
  }
  float* ob = outg + ((size_t)b * 133 + 128) * LPIX + h * 32 + w;
  ob[0 * LPIX] = m0;
  ob[1 * LPIX] = m1;
  ob[2 * LPIX] = var0;
  ob[3 * LPIX] = var1;
  ob[4 * LPIX] = cov;
}

extern "C" void kernel_launch(void* const* d_in, const int* in_sizes, int n_in,
                              void* d_out, int out_size, void* d_ws, size_t ws_size,
                              hipStream_t stream) {
  const float* x  = (const float*)d_in[0];
  const float* cw = (const float*)d_in[1];
  const float* cb = (const float*)d_in[2];
  const float* w2 = (const float*)d_in[3];
  const float* b2 = (const float*)d_in[4];
  const float* sk = (const float*)d_in[5];
  float* out = (float*)d_out;

  unsigned short* wmf = (unsigned short*)((char*)d_ws + WMF_OFF);
  float* qp = (float*)((char*)d_ws + QP_OFF);

  prepW<<<dim3(288), dim3(256), 0, stream>>>(cw, wmf);
  convFused<<<dim3(512), dim3(512), 0, stream>>>(x, wmf, cb, w2, sk, qp, out);
  statsB<<<dim3(256), dim3(64), 0, stream>>>(x, qp, b2, out);
}